// Round 5
// baseline (190.711 us; speedup 1.0000x reference)
//
#include <hip/hip_runtime.h>
#include <hip/hip_fp16.h>

#define HEADS 4
#define DH    32
#define HW    4096
#define CIN   256
#define HID   128

using half8   = __attribute__((ext_vector_type(8))) _Float16;
using half4   = __attribute__((ext_vector_type(4))) _Float16;
using floatx4 = __attribute__((ext_vector_type(4))) float;

// exp shift: P = exp2(s*log2e - 3*log2e); log2e folded into Q pre-scale
#define SHIFT2 4.328085122666891f

// ---------------------------------------------------------------------------
// conv_w: w_qkv (384x256) -> f16. Q rows pre-scaled by 32^-0.5 * log2(e) so
// attention scores arrive in log2 domain. w_out -> f16.
// ---------------------------------------------------------------------------
__global__ __launch_bounds__(256) void conv_w(
    const float* __restrict__ wq, const float* __restrict__ wo,
    _Float16* __restrict__ Wh, _Float16* __restrict__ Woh)
{
  const int idx = blockIdx.x * 256 + threadIdx.x;
  const int n1 = 384 * CIN;
  if (idx < n1) {
    // 32^-0.5 * log2(e) = 0.1767766953 * 1.4426950409
    float s = (idx < 128 * CIN) ? 0.25508275947f : 1.0f;
    Wh[idx] = (_Float16)(wq[idx] * s);
  } else {
    Woh[idx - n1] = (_Float16)wo[idx - n1];
  }
}

// ---------------------------------------------------------------------------
// qkv_gemm (fused x-transpose): QKV[o][b,p] = Wh(384x256) @ x^T.
// B staged straight from fp32 x [b][c][p]: coalesced float4 row reads,
// transposed f16 writes into Bs. Tile 64(o) x 64(p), K=256 in 2 halves.
// Epilogue scatters Qw/Kw [bh][p][d] (8B) and Vtw [bh][d][p].
// grid (6 m-tiles, 256 n-tiles) x 256
// ---------------------------------------------------------------------------
__global__ __launch_bounds__(256) void qkv_gemm(
    const _Float16* __restrict__ Wh, const float* __restrict__ x,
    _Float16* __restrict__ Qw, _Float16* __restrict__ Kw,
    _Float16* __restrict__ Vtw)
{
  __shared__ _Float16 As[64][136];
  __shared__ _Float16 Bs[64][136];
  const int mt = blockIdx.x, nt = blockIdx.y;
  const int b = nt >> 6, p0 = (nt & 63) * 64;
  const int tid = threadIdx.x;
  const int wv = tid >> 6, lane = tid & 63, lm = lane & 15, quad = lane >> 4;

  const _Float16* A = Wh + (size_t)mt * 64 * CIN;
  const float* xb = x + (size_t)b * CIN * HW + p0;

  floatx4 acc[4] = {{0,0,0,0},{0,0,0,0},{0,0,0,0},{0,0,0,0}};

  #pragma unroll
  for (int kh = 0; kh < 2; ++kh) {
    __syncthreads();
    // A: 64 rows x 128 halves = 1024 chunks of 8
    #pragma unroll
    for (int i = 0; i < 4; ++i) {
      int ci = tid + i * 256;
      int r = ci >> 4, c8 = (ci & 15) * 8;
      *(half8*)&As[r][c8] = *(const half8*)(A + (size_t)r * CIN + kh * 128 + c8);
    }
    // B: x[kh*128 + c][p0 + pp] fp32, 128 c-rows x 16 float4 = 2048 chunks
    #pragma unroll
    for (int i = 0; i < 8; ++i) {
      int ci = tid + i * 256;
      int cr = ci >> 4, p4 = (ci & 15) * 4;
      float4 v = *(const float4*)(xb + (size_t)(kh * 128 + cr) * HW + p4);
      Bs[p4 + 0][cr] = (_Float16)v.x;
      Bs[p4 + 1][cr] = (_Float16)v.y;
      Bs[p4 + 2][cr] = (_Float16)v.z;
      Bs[p4 + 3][cr] = (_Float16)v.w;
    }
    __syncthreads();
    #pragma unroll
    for (int ks = 0; ks < 4; ++ks) {
      half8 a = *(const half8*)&As[wv * 16 + lm][ks * 32 + quad * 8];
      #pragma unroll
      for (int ns = 0; ns < 4; ++ns) {
        half8 bf = *(const half8*)&Bs[ns * 16 + lm][ks * 32 + quad * 8];
        acc[ns] = __builtin_amdgcn_mfma_f32_16x16x32_f16(a, bf, acc[ns], 0, 0, 0);
      }
    }
  }

  // epilogue: m = wv*16 + quad*4 + r, n = ns*16 + lm
  const int sec = mt >> 1;                    // 0=Q 1=K 2=V
  const int o_base = (mt & 1) * 64 + wv * 16 + quad * 4;
  const int hh = o_base >> 5, dd = o_base & 31;
  const int bh = b * HEADS + hh;
  if (sec < 2) {
    _Float16* dst = (sec == 0) ? Qw : Kw;
    #pragma unroll
    for (int ns = 0; ns < 4; ++ns) {
      int p = p0 + ns * 16 + lm;
      half4 v = {(_Float16)acc[ns][0], (_Float16)acc[ns][1],
                 (_Float16)acc[ns][2], (_Float16)acc[ns][3]};
      *(half4*)(dst + ((size_t)bh * HW + p) * DH + dd) = v;
    }
  } else {
    #pragma unroll
    for (int ns = 0; ns < 4; ++ns) {
      int p = p0 + ns * 16 + lm;
      #pragma unroll
      for (int r = 0; r < 4; ++r)
        Vtw[((size_t)bh * DH + dd + r) * HW + p] = (_Float16)acc[ns][r];
    }
  }
}

// ---------------------------------------------------------------------------
// attn: flash attention, no-max softmax in log2 domain (scores pre-scaled by
// log2e; P = exp2(s - 3*log2e), uniform shift cancels in normalization).
// Row sums via ones-MFMA into AGPRs. O^T = V^T @ P^T -> lane-local epilogue.
// ps stride 68 halves: P-store banks = quad*8 + lm/2 (+const) -> conflict-free.
// grid (64 q-tiles, 16 bh) x 256; wave w owns q-rows [qt*64+w*16, +16).
// ---------------------------------------------------------------------------
__global__ __launch_bounds__(256) void attn(
    const _Float16* __restrict__ Qw, const _Float16* __restrict__ Kw,
    const _Float16* __restrict__ Vtw, _Float16* __restrict__ Ot)
{
  __shared__ _Float16 ks[64][40];             // K tile [kcol][d]
  __shared__ _Float16 vt[32][72];             // V^T tile [d][kcol]
  __shared__ _Float16 ps[4][16][68];          // per-wave P [qrow][kcol], stride 68

  const int bh = blockIdx.y, qt = blockIdx.x;
  const int tid = threadIdx.x;
  const int wv = tid >> 6, lane = tid & 63, lm = lane & 15, quad = lane >> 4;

  const _Float16* qptr = Qw + ((size_t)bh * HW + qt * 64 + wv * 16 + lm) * DH + quad * 8;
  const half8 qa = *(const half8*)qptr;

  const _Float16 one = (_Float16)1.0f;
  const half8 ones = {one, one, one, one, one, one, one, one};

  floatx4 oT[2]  = {{0,0,0,0},{0,0,0,0}};     // O^T rows d=f*16+quad*4+r, col q=lm
  floatx4 l_acc  = {0,0,0,0};                 // rowsum(P) for qrow=lm

  const _Float16* kbase = Kw  + (size_t)bh * HW * DH;
  const _Float16* vbase = Vtw + (size_t)bh * DH * HW;
  const int kr = tid >> 2, kc = (tid & 3) * 8;
  const int vr = tid >> 3, vc = (tid & 7) * 8;

  // register prefetch double-buffer (final-iter overrun stays inside d_ws)
  half8 kpre = *(const half8*)(kbase + (size_t)kr * DH + kc);
  half8 vpre = *(const half8*)(vbase + (size_t)vr * HW + vc);

  for (int kt = 0; kt < HW / 64; ++kt) {
    __syncthreads();
    *(half8*)&ks[kr][kc] = kpre;
    *(half8*)&vt[vr][vc] = vpre;
    __syncthreads();
    kpre = *(const half8*)(kbase + ((size_t)(kt + 1) * 64 + kr) * DH + kc);
    vpre = *(const half8*)(vbase + (size_t)vr * HW + (kt + 1) * 64 + vc);

    // S = Q K^T (log2 domain): C[m=qrow_local][n=kcol f*16+lm]
    floatx4 s[4];
    #pragma unroll
    for (int f = 0; f < 4; ++f) {
      half8 kb = *(const half8*)&ks[f * 16 + lm][quad * 8];
      floatx4 z = {0,0,0,0};
      s[f] = __builtin_amdgcn_mfma_f32_16x16x32_f16(qa, kb, z, 0, 0, 0);
    }

    // P = exp2(s - SHIFT2): one sub + one native v_exp per element
    #pragma unroll
    for (int f = 0; f < 4; ++f)
      #pragma unroll
      for (int r = 0; r < 4; ++r)
        ps[wv][quad * 4 + r][f * 16 + lm] =
            (_Float16)__builtin_amdgcn_exp2f(s[f][r] - SHIFT2);

    // O^T += V^T P^T ; l += rowsum(P) via ones-MFMA (same B-frag)
    #pragma unroll
    for (int a = 0; a < 2; ++a) {
      half8 pb = *(const half8*)&ps[wv][lm][a * 32 + quad * 8];
      l_acc = __builtin_amdgcn_mfma_f32_16x16x32_f16(ones, pb, l_acc, 0, 0, 0);
      #pragma unroll
      for (int f = 0; f < 2; ++f) {
        half8 va = *(const half8*)&vt[f * 16 + lm][a * 32 + quad * 8];
        oT[f] = __builtin_amdgcn_mfma_f32_16x16x32_f16(va, pb, oT[f], 0, 0, 0);
      }
    }
  }

  // epilogue: lane-local normalize, coalesced half4 stores -> Ot[b][p][hid]
  const float inv = 1.0f / l_acc[0];
  const int b = bh >> 2, hh = bh & 3;
  _Float16* obase = Ot + ((size_t)(b * HW + qt * 64 + wv * 16 + lm)) * HID + hh * DH;
  #pragma unroll
  for (int f = 0; f < 2; ++f) {
    half4 v = {(_Float16)(oT[f][0] * inv), (_Float16)(oT[f][1] * inv),
               (_Float16)(oT[f][2] * inv), (_Float16)(oT[f][3] * inv)};
    *(half4*)(obase + f * 16 + quad * 4) = v;
  }
}

// ---------------------------------------------------------------------------
// out_gemm: out[o][b,p] = Woh(256x128) @ Ot^T + bias. Tile 64x64, K=128.
// grid (4 m-tiles, 256 n-tiles) x 256. Coalesced fp32 stores via LDS.
// ---------------------------------------------------------------------------
__global__ __launch_bounds__(256) void out_gemm(
    const _Float16* __restrict__ Woh, const _Float16* __restrict__ Ot,
    const float* __restrict__ bo, float* __restrict__ out)
{
  __shared__ _Float16 As[64][136];
  __shared__ _Float16 Bs[64][136];
  __shared__ float os[64][68];
  const int mt = blockIdx.x, nt = blockIdx.y;
  const int b = nt >> 6, p0 = (nt & 63) * 64;
  const int tid = threadIdx.x;
  const int wv = tid >> 6, lane = tid & 63, lm = lane & 15, quad = lane >> 4;

  const _Float16* A = Woh + (size_t)mt * 64 * HID;
  const _Float16* B = Ot + ((size_t)b * HW + p0) * HID;

  #pragma unroll
  for (int i = 0; i < 4; ++i) {               // 64 rows x 16 chunks = 1024 chunks
    int ci = tid + i * 256;
    int r = ci >> 4, c8 = (ci & 15) * 8;
    *(half8*)&As[r][c8] = *(const half8*)(A + (size_t)r * HID + c8);
    *(half8*)&Bs[r][c8] = *(const half8*)(B + (size_t)r * HID + c8);
  }
  __syncthreads();

  floatx4 acc[4] = {{0,0,0,0},{0,0,0,0},{0,0,0,0},{0,0,0,0}};
  #pragma unroll
  for (int ks = 0; ks < 4; ++ks) {
    half8 a = *(const half8*)&As[wv * 16 + lm][ks * 32 + quad * 8];
    #pragma unroll
    for (int ns = 0; ns < 4; ++ns) {
      half8 bf = *(const half8*)&Bs[ns * 16 + lm][ks * 32 + quad * 8];
      acc[ns] = __builtin_amdgcn_mfma_f32_16x16x32_f16(a, bf, acc[ns], 0, 0, 0);
    }
  }

  #pragma unroll
  for (int ns = 0; ns < 4; ++ns)
    #pragma unroll
    for (int r = 0; r < 4; ++r)
      os[wv * 16 + quad * 4 + r][ns * 16 + lm] = acc[ns][r];
  __syncthreads();

  const int o = tid >> 2, pq = (tid & 3) * 16;
  const float bias = bo[mt * 64 + o];
  float* dst = out + ((size_t)(b * CIN + mt * 64 + o)) * HW + p0 + pq;
  #pragma unroll
  for (int j = 0; j < 4; ++j) {
    float4 v = *(const float4*)&os[o][pq + j * 4];
    v.x += bias; v.y += bias; v.z += bias; v.w += bias;
    *(float4*)(dst + j * 4) = v;
  }
}

// ---------------------------------------------------------------------------
extern "C" void kernel_launch(void* const* d_in, const int* in_sizes, int n_in,
                              void* d_out, int out_size, void* d_ws, size_t ws_size,
                              hipStream_t stream)
{
  const float* x     = (const float*)d_in[0];   // [4,256,64,64]
  const float* w_qkv = (const float*)d_in[1];   // [384,256]
  const float* w_out = (const float*)d_in[2];   // [256,128]
  const float* b_out = (const float*)d_in[3];   // [256]
  float* out = (float*)d_out;

  char* ws = (char*)d_ws;                       // ~20.6 MB used
  _Float16* Ot  = (_Float16*)(ws);              // 4 MB [4][4096][128]
  _Float16* Qw  = (_Float16*)(ws + (8u  << 20)); // 4 MB [bh][p][d], log2e-scaled
  _Float16* Kw  = (_Float16*)(ws + (12u << 20)); // 4 MB [bh][p][d]
  _Float16* Vtw = (_Float16*)(ws + (16u << 20)); // 4 MB [bh][d][p]
  _Float16* Wh  = (_Float16*)(ws + (20u << 20));            // 192 KB
  _Float16* Woh = (_Float16*)(ws + (20u << 20) + (256u << 10)); // 64 KB

  dim3 blk(256);
  conv_w<<<dim3(512), blk, 0, stream>>>(w_qkv, w_out, Wh, Woh);
  qkv_gemm<<<dim3(6, 256), blk, 0, stream>>>(Wh, x, Qw, Kw, Vtw);
  attn<<<dim3(64, 16), blk, 0, stream>>>(Qw, Kw, Vtw, Ot);
  out_gemm<<<dim3(4, 256), blk, 0, stream>>>(Woh, Ot, b_out, out);
}

// Round 6
// 167.584 us; speedup vs baseline: 1.1380x; 1.1380x over previous
//
#include <hip/hip_runtime.h>
#include <hip/hip_fp16.h>

#define HEADS 4
#define DH    32
#define HW    4096
#define CIN   256
#define HID   128

using half8   = __attribute__((ext_vector_type(8))) _Float16;
using half4   = __attribute__((ext_vector_type(4))) _Float16;
using floatx4 = __attribute__((ext_vector_type(4))) float;

// P = exp2(s_log2 - 3*log2e); log2(e) folded into Q pre-scale in conv_w
#define SHIFT2 4.328085122666891f

// ---------------------------------------------------------------------------
// conv_x: x [b][c][p] fp32 -> Xh [b][p][c] f16 (transpose via LDS)
// grid (64 p-tiles, 4 c-tiles, 4 b) x 256
// ---------------------------------------------------------------------------
__global__ __launch_bounds__(256) void conv_x(
    const float* __restrict__ x, _Float16* __restrict__ Xh)
{
  __shared__ float t[64][65];
  const int b = blockIdx.z, ct = blockIdx.y, pt = blockIdx.x;
  const int tid = threadIdx.x;
  const float* src = x + ((size_t)(b * CIN + ct * 64)) * HW + pt * 64;
  #pragma unroll
  for (int i = 0; i < 16; ++i) {
    int idx = tid + i * 256;
    int c = idx >> 6, p = idx & 63;
    t[c][p] = src[(size_t)c * HW + p];
  }
  __syncthreads();
  #pragma unroll
  for (int pass = 0; pass < 2; ++pass) {
    int p = (tid >> 3) + pass * 32;
    int c0 = (tid & 7) * 8;
    half8 v;
    #pragma unroll
    for (int j = 0; j < 8; ++j) v[j] = (_Float16)t[c0 + j][p];
    *(half8*)(Xh + ((size_t)(b * HW + pt * 64 + p)) * CIN + ct * 64 + c0) = v;
  }
}

// ---------------------------------------------------------------------------
// conv_w: w_qkv -> f16, Q rows pre-scaled by 32^-0.5 * log2(e); w_out -> f16
// ---------------------------------------------------------------------------
__global__ __launch_bounds__(256) void conv_w(
    const float* __restrict__ wq, const float* __restrict__ wo,
    _Float16* __restrict__ Wh, _Float16* __restrict__ Woh)
{
  const int idx = blockIdx.x * 256 + threadIdx.x;
  const int n1 = 384 * CIN;
  if (idx < n1) {
    float s = (idx < 128 * CIN) ? 0.25508275947f : 1.0f;  // 32^-.5 * log2e
    Wh[idx] = (_Float16)(wq[idx] * s);
  } else {
    Woh[idx - n1] = (_Float16)wo[idx - n1];
  }
}

// ---------------------------------------------------------------------------
// qkv_gemm: QKV[o][b,p] = Wh(384x256) @ Xh^T. Tile 64(o) x 64(p), K=256.
// Epilogue scatters Qw/Kw [bh][p][d] (8B) and Vtw [bh][d][p].
// grid (6 m-tiles, 256 n-tiles) x 256
// ---------------------------------------------------------------------------
__global__ __launch_bounds__(256) void qkv_gemm(
    const _Float16* __restrict__ Wh, const _Float16* __restrict__ Xh,
    _Float16* __restrict__ Qw, _Float16* __restrict__ Kw,
    _Float16* __restrict__ Vtw)
{
  __shared__ _Float16 As[64][136];
  __shared__ _Float16 Bs[64][136];
  const int mt = blockIdx.x, nt = blockIdx.y;
  const int b = nt >> 6, p0 = (nt & 63) * 64;
  const int tid = threadIdx.x;
  const int wv = tid >> 6, lane = tid & 63, lm = lane & 15, quad = lane >> 4;

  const _Float16* A = Wh + (size_t)mt * 64 * CIN;
  const _Float16* B = Xh + ((size_t)b * HW + p0) * CIN;

  floatx4 acc[4] = {{0,0,0,0},{0,0,0,0},{0,0,0,0},{0,0,0,0}};

  #pragma unroll
  for (int kh = 0; kh < 2; ++kh) {
    __syncthreads();
    #pragma unroll
    for (int i = 0; i < 4; ++i) {
      int ci = tid + i * 256;
      int r = ci >> 4, c8 = (ci & 15) * 8;
      *(half8*)&As[r][c8] = *(const half8*)(A + (size_t)r * CIN + kh * 128 + c8);
      *(half8*)&Bs[r][c8] = *(const half8*)(B + (size_t)r * CIN + kh * 128 + c8);
    }
    __syncthreads();
    #pragma unroll
    for (int ks = 0; ks < 4; ++ks) {
      half8 a = *(const half8*)&As[wv * 16 + lm][ks * 32 + quad * 8];
      #pragma unroll
      for (int ns = 0; ns < 4; ++ns) {
        half8 bf = *(const half8*)&Bs[ns * 16 + lm][ks * 32 + quad * 8];
        acc[ns] = __builtin_amdgcn_mfma_f32_16x16x32_f16(a, bf, acc[ns], 0, 0, 0);
      }
    }
  }

  const int sec = mt >> 1;                    // 0=Q 1=K 2=V
  const int o_base = (mt & 1) * 64 + wv * 16 + quad * 4;
  const int hh = o_base >> 5, dd = o_base & 31;
  const int bh = b * HEADS + hh;
  if (sec < 2) {
    _Float16* dst = (sec == 0) ? Qw : Kw;
    #pragma unroll
    for (int ns = 0; ns < 4; ++ns) {
      int p = p0 + ns * 16 + lm;
      half4 v = {(_Float16)acc[ns][0], (_Float16)acc[ns][1],
                 (_Float16)acc[ns][2], (_Float16)acc[ns][3]};
      *(half4*)(dst + ((size_t)bh * HW + p) * DH + dd) = v;
    }
  } else {
    #pragma unroll
    for (int ns = 0; ns < 4; ++ns) {
      int p = p0 + ns * 16 + lm;
      #pragma unroll
      for (int r = 0; r < 4; ++r)
        Vtw[((size_t)bh * DH + dd + r) * HW + p] = (_Float16)acc[ns][r];
    }
  }
}

// ---------------------------------------------------------------------------
// attn: register-dataflow flash attention.
// S^T = mfma_16x16x32(A=K-rows, B=Q^T): lane(lm,quad) reg r holds
// S^T[kcol=4q+r][qrow=lm] — exactly the B-operand layout of
// mfma_f32_16x16x16f16 (lane n holds k=4q+j). So P fragments feed PV
// straight from registers: no LDS round-trip, no shuffles.
// O^T = V^T P^T (A = V^T b64 frags); l via ones-MFMA. Ping-pong K/V LDS,
// ONE barrier per K-tile. grid (64 q-tiles, 16 bh) x 256.
// ---------------------------------------------------------------------------
__global__ __launch_bounds__(256) void attn(
    const _Float16* __restrict__ Qw, const _Float16* __restrict__ Kw,
    const _Float16* __restrict__ Vtw, _Float16* __restrict__ Ot)
{
  __shared__ _Float16 ks[2][64][40];          // K tile [kcol][d]
  __shared__ _Float16 vt[2][32][72];          // V^T tile [d][kcol]

  const int bh = blockIdx.y, qt = blockIdx.x;
  const int tid = threadIdx.x;
  const int wv = tid >> 6, lane = tid & 63, lm = lane & 15, quad = lane >> 4;

  const _Float16* qptr = Qw + ((size_t)bh * HW + qt * 64 + wv * 16 + lm) * DH + quad * 8;
  const half8 qa = *(const half8*)qptr;

  const _Float16 one = (_Float16)1.0f;
  const half4 ones4 = {one, one, one, one};

  floatx4 oT[2] = {{0,0,0,0},{0,0,0,0}};      // O^T[d=g*16+4q+r][qrow=lm]
  floatx4 l4    = {0,0,0,0};                  // rowsum(P) for qrow=lm

  const _Float16* kbase = Kw  + (size_t)bh * HW * DH;
  const _Float16* vbase = Vtw + (size_t)bh * DH * HW;
  const int kr = tid >> 2, kc = (tid & 3) * 8;
  const int vr = tid >> 3, vc = (tid & 7) * 8;

  // prologue: stage tile0, prefetch tile1 (overruns stay inside d_ws)
  half8 kpre = *(const half8*)(kbase + (size_t)kr * DH + kc);
  half8 vpre = *(const half8*)(vbase + (size_t)vr * HW + vc);
  *(half8*)&ks[0][kr][kc] = kpre;
  *(half8*)&vt[0][vr][vc] = vpre;
  kpre = *(const half8*)(kbase + ((size_t)64 + kr) * DH + kc);
  vpre = *(const half8*)(vbase + (size_t)vr * HW + 64 + vc);
  __syncthreads();

  for (int kt = 0; kt < HW / 64; ++kt) {
    const int cur = kt & 1;
    // stage next tile into the other buffer; prefetch tile kt+2
    *(half8*)&ks[cur ^ 1][kr][kc] = kpre;
    *(half8*)&vt[cur ^ 1][vr][vc] = vpre;
    kpre = *(const half8*)(kbase + ((size_t)(kt + 2) * 64 + kr) * DH + kc);
    vpre = *(const half8*)(vbase + (size_t)vr * HW + (kt + 2) * 64 + vc);

    // S^T = K Q^T (log2 domain)
    floatx4 sT[4];
    #pragma unroll
    for (int f = 0; f < 4; ++f) {
      half8 kb = *(const half8*)&ks[cur][f * 16 + lm][quad * 8];
      floatx4 z = {0,0,0,0};
      sT[f] = __builtin_amdgcn_mfma_f32_16x16x32_f16(kb, qa, z, 0, 0, 0);
    }

    // P^T fragments in-register: pb[f] is the 16x16x16 B-operand directly
    #pragma unroll
    for (int f = 0; f < 4; ++f) {
      half4 pb;
      #pragma unroll
      for (int r = 0; r < 4; ++r)
        pb[r] = (_Float16)__builtin_amdgcn_exp2f(sT[f][r] - SHIFT2);
      l4 = __builtin_amdgcn_mfma_f32_16x16x16f16(ones4, pb, l4, 0, 0, 0);
      #pragma unroll
      for (int g = 0; g < 2; ++g) {
        half4 va = *(const half4*)&vt[cur][g * 16 + lm][f * 16 + quad * 4];
        oT[g] = __builtin_amdgcn_mfma_f32_16x16x16f16(va, pb, oT[g], 0, 0, 0);
      }
    }
    __syncthreads();                          // single barrier per tile
  }

  // epilogue: lane-local normalize, coalesced half4 stores -> Ot[b][p][hid]
  const float inv = 1.0f / l4[0];
  const int b = bh >> 2, hh = bh & 3;
  _Float16* obase = Ot + ((size_t)(b * HW + qt * 64 + wv * 16 + lm)) * HID + hh * DH;
  #pragma unroll
  for (int g = 0; g < 2; ++g) {
    half4 v = {(_Float16)(oT[g][0] * inv), (_Float16)(oT[g][1] * inv),
               (_Float16)(oT[g][2] * inv), (_Float16)(oT[g][3] * inv)};
    *(half4*)(obase + g * 16 + quad * 4) = v;
  }
}

// ---------------------------------------------------------------------------
// out_gemm: out[o][b,p] = Woh(256x128) @ Ot^T + bias. Tile 64x64, K=128.
// grid (4 m-tiles, 256 n-tiles) x 256. Coalesced fp32 stores via LDS.
// ---------------------------------------------------------------------------
__global__ __launch_bounds__(256) void out_gemm(
    const _Float16* __restrict__ Woh, const _Float16* __restrict__ Ot,
    const float* __restrict__ bo, float* __restrict__ out)
{
  __shared__ _Float16 As[64][136];
  __shared__ _Float16 Bs[64][136];
  __shared__ float os[64][68];
  const int mt = blockIdx.x, nt = blockIdx.y;
  const int b = nt >> 6, p0 = (nt & 63) * 64;
  const int tid = threadIdx.x;
  const int wv = tid >> 6, lane = tid & 63, lm = lane & 15, quad = lane >> 4;

  const _Float16* A = Woh + (size_t)mt * 64 * HID;
  const _Float16* B = Ot + ((size_t)b * HW + p0) * HID;

  #pragma unroll
  for (int i = 0; i < 4; ++i) {               // 64 rows x 16 chunks = 1024
    int ci = tid + i * 256;
    int r = ci >> 4, c8 = (ci & 15) * 8;
    *(half8*)&As[r][c8] = *(const half8*)(A + (size_t)r * HID + c8);
    *(half8*)&Bs[r][c8] = *(const half8*)(B + (size_t)r * HID + c8);
  }
  __syncthreads();

  floatx4 acc[4] = {{0,0,0,0},{0,0,0,0},{0,0,0,0},{0,0,0,0}};
  #pragma unroll
  for (int ks = 0; ks < 4; ++ks) {
    half8 a = *(const half8*)&As[wv * 16 + lm][ks * 32 + quad * 8];
    #pragma unroll
    for (int ns = 0; ns < 4; ++ns) {
      half8 bf = *(const half8*)&Bs[ns * 16 + lm][ks * 32 + quad * 8];
      acc[ns] = __builtin_amdgcn_mfma_f32_16x16x32_f16(a, bf, acc[ns], 0, 0, 0);
    }
  }

  #pragma unroll
  for (int ns = 0; ns < 4; ++ns)
    #pragma unroll
    for (int r = 0; r < 4; ++r)
      os[wv * 16 + quad * 4 + r][ns * 16 + lm] = acc[ns][r];
  __syncthreads();

  const int o = tid >> 2, pq = (tid & 3) * 16;
  const float bias = bo[mt * 64 + o];
  float* dst = out + ((size_t)(b * CIN + mt * 64 + o)) * HW + p0 + pq;
  #pragma unroll
  for (int j = 0; j < 4; ++j) {
    float4 v = *(const float4*)&os[o][pq + j * 4];
    v.x += bias; v.y += bias; v.z += bias; v.w += bias;
    *(float4*)(dst + j * 4) = v;
  }
}

// ---------------------------------------------------------------------------
extern "C" void kernel_launch(void* const* d_in, const int* in_sizes, int n_in,
                              void* d_out, int out_size, void* d_ws, size_t ws_size,
                              hipStream_t stream)
{
  const float* x     = (const float*)d_in[0];   // [4,256,64,64]
  const float* w_qkv = (const float*)d_in[1];   // [384,256]
  const float* w_out = (const float*)d_in[2];   // [256,128]
  const float* b_out = (const float*)d_in[3];   // [256]
  float* out = (float*)d_out;

  char* ws = (char*)d_ws;                       // ~20.6 MB used
  _Float16* Xh  = (_Float16*)(ws);              // 8 MB [4][4096][256]
  _Float16* Ot  = (_Float16*)(ws);              // 4 MB (reuses Xh after qkv)
  _Float16* Qw  = (_Float16*)(ws + (8u  << 20)); // 4 MB [bh][p][d], log2e-scaled
  _Float16* Kw  = (_Float16*)(ws + (12u << 20)); // 4 MB [bh][p][d]
  _Float16* Vtw = (_Float16*)(ws + (16u << 20)); // 4 MB [bh][d][p]
  _Float16* Wh  = (_Float16*)(ws + (20u << 20));            // 192 KB
  _Float16* Woh = (_Float16*)(ws + (20u << 20) + (256u << 10)); // 64 KB

  dim3 blk(256);
  conv_x<<<dim3(64, 4, 4), blk, 0, stream>>>(x, Xh);
  conv_w<<<dim3(512), blk, 0, stream>>>(w_qkv, w_out, Wh, Woh);
  qkv_gemm<<<dim3(6, 256), blk, 0, stream>>>(Wh, Xh, Qw, Kw, Vtw);
  attn<<<dim3(64, 16), blk, 0, stream>>>(Qw, Kw, Vtw, Ot);
  out_gemm<<<dim3(4, 256), blk, 0, stream>>>(Woh, Ot, b_out, out);
}

// Round 7
// 165.445 us; speedup vs baseline: 1.1527x; 1.0129x over previous
//
#include <hip/hip_runtime.h>
#include <hip/hip_fp16.h>

#define HEADS 4
#define DH    32
#define HW    4096
#define CIN   256
#define HID   128

using half8   = __attribute__((ext_vector_type(8))) _Float16;
using half4   = __attribute__((ext_vector_type(4))) _Float16;
using floatx4 = __attribute__((ext_vector_type(4))) float;

// P = exp2(s_log2 - 3*log2e); log2(e) folded into Q pre-scale, shift folded
// into the S-MFMA C-initializer.
#define SHIFT2 4.328085122666891f
#define WQSCALE 0.25508275947f   // 32^-0.5 * log2(e)

// ---------------------------------------------------------------------------
// qkv_fused: QKV[o][b,p] = (w_qkv f32->f16, Q rows pre-scaled) @ x^T.
// x transposed through fp32 t[64][65] LDS tile (conflict-free column reads),
// K processed in 4 quarters of 64. Tile 64(o) x 64(p).
// Epilogue scatters Qw/Kw [bh][p][d] (8B) and Vtw [bh][d][p].
// grid (6 m-tiles, 256 n-tiles) x 256
// ---------------------------------------------------------------------------
__global__ __launch_bounds__(256) void qkv_fused(
    const float* __restrict__ w, const float* __restrict__ x,
    _Float16* __restrict__ Qw, _Float16* __restrict__ Kw,
    _Float16* __restrict__ Vtw)
{
  __shared__ float t[64][65];                 // 16.6 KB
  __shared__ _Float16 As[64][72];             // 9.2 KB
  __shared__ _Float16 Bs[64][72];             // 9.2 KB  -> 35 KB total
  const int mt = blockIdx.x, nt = blockIdx.y;
  const int b = nt >> 6, p0 = (nt & 63) * 64;
  const int tid = threadIdx.x;
  const int wv = tid >> 6, lane = tid & 63, lm = lane & 15, quad = lane >> 4;
  const float wscale = (mt < 2) ? WQSCALE : 1.0f;

  const float* Ag = w + (size_t)(mt * 64) * CIN;
  const float* xb = x + (size_t)b * CIN * HW + p0;

  floatx4 acc[4] = {{0,0,0,0},{0,0,0,0},{0,0,0,0},{0,0,0,0}};

  for (int kq = 0; kq < 4; ++kq) {
    __syncthreads();                          // prev quarter fully consumed
    // stage x quarter: c in [kq*64, +64), p in [p0, +64) -> t (fp32)
    #pragma unroll
    for (int i = 0; i < 4; ++i) {
      int ci = tid + i * 256;
      int cc = ci >> 4, p4 = (ci & 15) * 4;
      *(float4*)&t[cc][p4] =
          *(const float4*)(xb + (size_t)(kq * 64 + cc) * HW + p4);
    }
    // stage As quarter with inline cvt+scale: w rows mt*64..+64, c kq*64..+64
    #pragma unroll
    for (int i = 0; i < 2; ++i) {
      int ci = tid + i * 256;
      int r = ci >> 3, c8 = (ci & 7) * 8;
      const float* src = Ag + (size_t)r * CIN + kq * 64 + c8;
      float4 u0 = *(const float4*)(src);
      float4 u1 = *(const float4*)(src + 4);
      half8 h = {(_Float16)(u0.x * wscale), (_Float16)(u0.y * wscale),
                 (_Float16)(u0.z * wscale), (_Float16)(u0.w * wscale),
                 (_Float16)(u1.x * wscale), (_Float16)(u1.y * wscale),
                 (_Float16)(u1.z * wscale), (_Float16)(u1.w * wscale)};
      *(half8*)&As[r][c8] = h;
    }
    __syncthreads();                          // t ready
    // build Bs: transpose t -> Bs[p][c] f16 (column reads conflict-free)
    #pragma unroll
    for (int i = 0; i < 2; ++i) {
      int idx = tid + i * 256;
      int p = idx >> 3, c0 = (idx & 7) * 8;
      half8 v;
      #pragma unroll
      for (int k = 0; k < 8; ++k) v[k] = (_Float16)t[c0 + k][p];
      *(half8*)&Bs[p][c0] = v;
    }
    __syncthreads();                          // As/Bs ready
    #pragma unroll
    for (int ks = 0; ks < 2; ++ks) {
      half8 a = *(const half8*)&As[wv * 16 + lm][ks * 32 + quad * 8];
      #pragma unroll
      for (int ns = 0; ns < 4; ++ns) {
        half8 bf = *(const half8*)&Bs[ns * 16 + lm][ks * 32 + quad * 8];
        acc[ns] = __builtin_amdgcn_mfma_f32_16x16x32_f16(a, bf, acc[ns], 0, 0, 0);
      }
    }
  }

  // epilogue: m = wv*16 + quad*4 + r, n = ns*16 + lm
  const int sec = mt >> 1;                    // 0=Q 1=K 2=V
  const int o_base = (mt & 1) * 64 + wv * 16 + quad * 4;
  const int hh = o_base >> 5, dd = o_base & 31;
  const int bh = b * HEADS + hh;
  if (sec < 2) {
    _Float16* dst = (sec == 0) ? Qw : Kw;
    #pragma unroll
    for (int ns = 0; ns < 4; ++ns) {
      int p = p0 + ns * 16 + lm;
      half4 v = {(_Float16)acc[ns][0], (_Float16)acc[ns][1],
                 (_Float16)acc[ns][2], (_Float16)acc[ns][3]};
      *(half4*)(dst + ((size_t)bh * HW + p) * DH + dd) = v;
    }
  } else {
    #pragma unroll
    for (int ns = 0; ns < 4; ++ns) {
      int p = p0 + ns * 16 + lm;
      #pragma unroll
      for (int r = 0; r < 4; ++r)
        Vtw[((size_t)bh * DH + dd + r) * HW + p] = (_Float16)acc[ns][r];
    }
  }
}

// ---------------------------------------------------------------------------
// attn: register-dataflow flash attention, 128-wide K-step (2 subtiles per
// barrier, ping-pong buffers). S^T = mfma(A=K-rows, B=Q^T, C=-SHIFT2);
// P^T fragments stay in registers (16x16x16 B-operand layout, HW-verified
// round 6). O^T = V^T P^T; row sums via ones-MFMA. One barrier per 128 kcols,
// prefetch issued ~2 subtile-computes ahead of use.
// grid (64 q-tiles, 16 bh) x 256; wave w owns q-rows [qt*64+w*16, +16).
// ---------------------------------------------------------------------------
__global__ __launch_bounds__(256) void attn(
    const _Float16* __restrict__ Qw, const _Float16* __restrict__ Kw,
    const _Float16* __restrict__ Vtw, _Float16* __restrict__ Ot)
{
  __shared__ _Float16 ks[2][2][64][40];       // [phase][sub][kcol][d] 20.5 KB
  __shared__ _Float16 vt[2][2][32][72];       // [phase][sub][d][kcol] 18.4 KB

  const int bh = blockIdx.y, qt = blockIdx.x;
  const int tid = threadIdx.x;
  const int wv = tid >> 6, lane = tid & 63, lm = lane & 15, quad = lane >> 4;

  const _Float16* qptr = Qw + ((size_t)bh * HW + qt * 64 + wv * 16 + lm) * DH + quad * 8;
  const half8 qa = *(const half8*)qptr;

  const _Float16 one = (_Float16)1.0f;
  const half4 ones4 = {one, one, one, one};
  const floatx4 shiftc = {-SHIFT2, -SHIFT2, -SHIFT2, -SHIFT2};

  floatx4 oT[2] = {{0,0,0,0},{0,0,0,0}};      // O^T[d=g*16+4q+r][qrow=lm]
  floatx4 l4    = {0,0,0,0};                  // rowsum(P) for qrow=lm

  const _Float16* kbase = Kw  + (size_t)bh * HW * DH;
  const _Float16* vbase = Vtw + (size_t)bh * DH * HW;
  const int kr = tid >> 2, kc = (tid & 3) * 8;
  const int vr = tid >> 3, vc = (tid & 7) * 8;

  // prologue: stage subtiles 0,1; prefetch 2,3 (overruns stay inside d_ws)
  half8 kA = *(const half8*)(kbase + (size_t)kr * DH + kc);
  half8 vA = *(const half8*)(vbase + (size_t)vr * HW + vc);
  half8 kB = *(const half8*)(kbase + ((size_t)64 + kr) * DH + kc);
  half8 vB = *(const half8*)(vbase + (size_t)vr * HW + 64 + vc);
  *(half8*)&ks[0][0][kr][kc] = kA;
  *(half8*)&vt[0][0][vr][vc] = vA;
  *(half8*)&ks[0][1][kr][kc] = kB;
  *(half8*)&vt[0][1][vr][vc] = vB;
  kA = *(const half8*)(kbase + ((size_t)128 + kr) * DH + kc);
  vA = *(const half8*)(vbase + (size_t)vr * HW + 128 + vc);
  kB = *(const half8*)(kbase + ((size_t)192 + kr) * DH + kc);
  vB = *(const half8*)(vbase + (size_t)vr * HW + 192 + vc);
  __syncthreads();

  for (int it = 0; it < HW / 128; ++it) {
    const int ph = it & 1, nx = ph ^ 1;
    // write prefetched subtiles (2it+2, 2it+3) into the other phase
    *(half8*)&ks[nx][0][kr][kc] = kA;
    *(half8*)&vt[nx][0][vr][vc] = vA;
    *(half8*)&ks[nx][1][kr][kc] = kB;
    *(half8*)&vt[nx][1][vr][vc] = vB;
    // prefetch subtiles (2it+4, 2it+5)
    const size_t koff = (size_t)(it * 2 + 4) * 64;
    kA = *(const half8*)(kbase + (koff + kr) * DH + kc);
    vA = *(const half8*)(vbase + (size_t)vr * HW + koff + vc);
    kB = *(const half8*)(kbase + (koff + 64 + kr) * DH + kc);
    vB = *(const half8*)(vbase + (size_t)vr * HW + koff + 64 + vc);

    #pragma unroll
    for (int sub = 0; sub < 2; ++sub) {
      // S^T = K Q^T - SHIFT2 (shift folded into C)
      floatx4 sT[4];
      #pragma unroll
      for (int f = 0; f < 4; ++f) {
        half8 kb = *(const half8*)&ks[ph][sub][f * 16 + lm][quad * 8];
        sT[f] = __builtin_amdgcn_mfma_f32_16x16x32_f16(kb, qa, shiftc, 0, 0, 0);
      }
      // P^T fragments in-register -> PV + rowsum MFMAs
      #pragma unroll
      for (int f = 0; f < 4; ++f) {
        half4 pb;
        #pragma unroll
        for (int r = 0; r < 4; ++r)
          pb[r] = (_Float16)__builtin_amdgcn_exp2f(sT[f][r]);
        l4 = __builtin_amdgcn_mfma_f32_16x16x16f16(ones4, pb, l4, 0, 0, 0);
        #pragma unroll
        for (int g = 0; g < 2; ++g) {
          half4 va = *(const half4*)&vt[ph][sub][g * 16 + lm][f * 16 + quad * 4];
          oT[g] = __builtin_amdgcn_mfma_f32_16x16x16f16(va, pb, oT[g], 0, 0, 0);
        }
      }
    }
    __syncthreads();                          // one barrier per 128 kcols
  }

  // epilogue: lane-local normalize, coalesced half4 stores -> Ot[b][p][hid]
  const float inv = 1.0f / l4[0];
  const int b = bh >> 2, hh = bh & 3;
  _Float16* obase = Ot + ((size_t)(b * HW + qt * 64 + wv * 16 + lm)) * HID + hh * DH;
  #pragma unroll
  for (int g = 0; g < 2; ++g) {
    half4 v = {(_Float16)(oT[g][0] * inv), (_Float16)(oT[g][1] * inv),
               (_Float16)(oT[g][2] * inv), (_Float16)(oT[g][3] * inv)};
    *(half4*)(obase + g * 16 + quad * 4) = v;
  }
}

// ---------------------------------------------------------------------------
// out_gemm: out[o][b,p] = w_out(256x128, cvt inline) @ Ot^T + bias.
// Tile 64x64, K=128. grid (4 m-tiles, 256 n-tiles) x 256.
// ---------------------------------------------------------------------------
__global__ __launch_bounds__(256) void out_gemm(
    const float* __restrict__ wo, const _Float16* __restrict__ Ot,
    const float* __restrict__ bo, float* __restrict__ out)
{
  __shared__ _Float16 As[64][136];
  __shared__ _Float16 Bs[64][136];
  __shared__ float os[64][68];
  const int mt = blockIdx.x, nt = blockIdx.y;
  const int b = nt >> 6, p0 = (nt & 63) * 64;
  const int tid = threadIdx.x;
  const int wv = tid >> 6, lane = tid & 63, lm = lane & 15, quad = lane >> 4;

  const float* Ag = wo + (size_t)(mt * 64) * HID;
  const _Float16* B = Ot + ((size_t)b * HW + p0) * HID;

  #pragma unroll
  for (int i = 0; i < 4; ++i) {               // 64 rows x 16 chunks = 1024
    int ci = tid + i * 256;
    int r = ci >> 4, c8 = (ci & 15) * 8;
    const float* src = Ag + (size_t)r * HID + c8;
    float4 u0 = *(const float4*)(src);
    float4 u1 = *(const float4*)(src + 4);
    half8 h = {(_Float16)u0.x, (_Float16)u0.y, (_Float16)u0.z, (_Float16)u0.w,
               (_Float16)u1.x, (_Float16)u1.y, (_Float16)u1.z, (_Float16)u1.w};
    *(half8*)&As[r][c8] = h;
    *(half8*)&Bs[r][c8] = *(const half8*)(B + (size_t)r * HID + c8);
  }
  __syncthreads();

  floatx4 acc[4] = {{0,0,0,0},{0,0,0,0},{0,0,0,0},{0,0,0,0}};
  #pragma unroll
  for (int ks = 0; ks < 4; ++ks) {
    half8 a = *(const half8*)&As[wv * 16 + lm][ks * 32 + quad * 8];
    #pragma unroll
    for (int ns = 0; ns < 4; ++ns) {
      half8 bf = *(const half8*)&Bs[ns * 16 + lm][ks * 32 + quad * 8];
      acc[ns] = __builtin_amdgcn_mfma_f32_16x16x32_f16(a, bf, acc[ns], 0, 0, 0);
    }
  }

  #pragma unroll
  for (int ns = 0; ns < 4; ++ns)
    #pragma unroll
    for (int r = 0; r < 4; ++r)
      os[wv * 16 + quad * 4 + r][ns * 16 + lm] = acc[ns][r];
  __syncthreads();

  const int o = tid >> 2, pq = (tid & 3) * 16;
  const float bias = bo[mt * 64 + o];
  float* dst = out + ((size_t)(b * CIN + mt * 64 + o)) * HW + p0 + pq;
  #pragma unroll
  for (int j = 0; j < 4; ++j) {
    float4 v = *(const float4*)&os[o][pq + j * 4];
    v.x += bias; v.y += bias; v.z += bias; v.w += bias;
    *(float4*)(dst + j * 4) = v;
  }
}

// ---------------------------------------------------------------------------
extern "C" void kernel_launch(void* const* d_in, const int* in_sizes, int n_in,
                              void* d_out, int out_size, void* d_ws, size_t ws_size,
                              hipStream_t stream)
{
  const float* x     = (const float*)d_in[0];   // [4,256,64,64]
  const float* w_qkv = (const float*)d_in[1];   // [384,256]
  const float* w_out = (const float*)d_in[2];   // [256,128]
  const float* b_out = (const float*)d_in[3];   // [256]
  float* out = (float*)d_out;

  char* ws = (char*)d_ws;                       // ~20.1 MB touched (incl. overrun slack)
  _Float16* Ot  = (_Float16*)(ws);              // 4 MB [4][4096][128]
  _Float16* Qw  = (_Float16*)(ws + (8u  << 20)); // 4 MB [bh][p][d], log2e-scaled
  _Float16* Kw  = (_Float16*)(ws + (12u << 20)); // 4 MB [bh][p][d]
  _Float16* Vtw = (_Float16*)(ws + (16u << 20)); // 4 MB [bh][d][p]

  dim3 blk(256);
  qkv_fused<<<dim3(6, 256), blk, 0, stream>>>(w_qkv, x, Qw, Kw, Vtw);
  attn<<<dim3(64, 16), blk, 0, stream>>>(Qw, Kw, Vtw, Ot);
  out_gemm<<<dim3(4, 256), blk, 0, stream>>>(w_out, Ot, b_out, out);
}

// Round 9
// 164.956 us; speedup vs baseline: 1.1561x; 1.0030x over previous
//
#include <hip/hip_runtime.h>
#include <hip/hip_fp16.h>

#define HEADS 4
#define DH    32
#define HW    4096
#define CIN   256
#define HID   128

using half8   = __attribute__((ext_vector_type(8))) _Float16;
using half4   = __attribute__((ext_vector_type(4))) _Float16;
using half2v  = __attribute__((ext_vector_type(2))) _Float16;
using floatx4 = __attribute__((ext_vector_type(4))) float;

// P = exp2(s_log2 - 3*log2e); log2(e) folded into Q pre-scale, shift folded
// into the S-MFMA C-initializer.
#define SHIFT2 4.328085122666891f
#define WQSCALE 0.25508275947f   // 32^-0.5 * log2(e)

// packed f32x2 -> f16x2 (cvt_pkrtz returns __fp16 vec; bit-cast to _Float16 vec)
static __device__ __forceinline__ half2v pk2(float a, float b) {
  return __builtin_bit_cast(half2v, __builtin_amdgcn_cvt_pkrtz(a, b));
}

// ---------------------------------------------------------------------------
// qkv_fused: QKV[o][b,p] = (w_qkv f32->f16, Q rows pre-scaled) @ x^T.
// x transposed through fp32 t[64][65] LDS tile, K in 4 quarters of 64.
// grid (6 m-tiles, 256 n-tiles) x 256
// ---------------------------------------------------------------------------
__global__ __launch_bounds__(256) void qkv_fused(
    const float* __restrict__ w, const float* __restrict__ x,
    _Float16* __restrict__ Qw, _Float16* __restrict__ Kw,
    _Float16* __restrict__ Vtw)
{
  __shared__ float t[64][65];
  __shared__ _Float16 As[64][72];
  __shared__ _Float16 Bs[64][72];
  const int mt = blockIdx.x, nt = blockIdx.y;
  const int b = nt >> 6, p0 = (nt & 63) * 64;
  const int tid = threadIdx.x;
  const int wv = tid >> 6, lane = tid & 63, lm = lane & 15, quad = lane >> 4;
  const float wscale = (mt < 2) ? WQSCALE : 1.0f;

  const float* Ag = w + (size_t)(mt * 64) * CIN;
  const float* xb = x + (size_t)b * CIN * HW + p0;

  floatx4 acc[4] = {{0,0,0,0},{0,0,0,0},{0,0,0,0},{0,0,0,0}};

  for (int kq = 0; kq < 4; ++kq) {
    __syncthreads();
    #pragma unroll
    for (int i = 0; i < 4; ++i) {
      int ci = tid + i * 256;
      int cc = ci >> 4, p4 = (ci & 15) * 4;
      *(float4*)&t[cc][p4] =
          *(const float4*)(xb + (size_t)(kq * 64 + cc) * HW + p4);
    }
    #pragma unroll
    for (int i = 0; i < 2; ++i) {
      int ci = tid + i * 256;
      int r = ci >> 3, c8 = (ci & 7) * 8;
      const float* src = Ag + (size_t)r * CIN + kq * 64 + c8;
      float4 u0 = *(const float4*)(src);
      float4 u1 = *(const float4*)(src + 4);
      half8 h = {(_Float16)(u0.x * wscale), (_Float16)(u0.y * wscale),
                 (_Float16)(u0.z * wscale), (_Float16)(u0.w * wscale),
                 (_Float16)(u1.x * wscale), (_Float16)(u1.y * wscale),
                 (_Float16)(u1.z * wscale), (_Float16)(u1.w * wscale)};
      *(half8*)&As[r][c8] = h;
    }
    __syncthreads();
    #pragma unroll
    for (int i = 0; i < 2; ++i) {
      int idx = tid + i * 256;
      int p = idx >> 3, c0 = (idx & 7) * 8;
      half8 v;
      #pragma unroll
      for (int k = 0; k < 8; ++k) v[k] = (_Float16)t[c0 + k][p];
      *(half8*)&Bs[p][c0] = v;
    }
    __syncthreads();
    #pragma unroll
    for (int ks = 0; ks < 2; ++ks) {
      half8 a = *(const half8*)&As[wv * 16 + lm][ks * 32 + quad * 8];
      #pragma unroll
      for (int ns = 0; ns < 4; ++ns) {
        half8 bf = *(const half8*)&Bs[ns * 16 + lm][ks * 32 + quad * 8];
        acc[ns] = __builtin_amdgcn_mfma_f32_16x16x32_f16(a, bf, acc[ns], 0, 0, 0);
      }
    }
  }

  const int sec = mt >> 1;                    // 0=Q 1=K 2=V
  const int o_base = (mt & 1) * 64 + wv * 16 + quad * 4;
  const int hh = o_base >> 5, dd = o_base & 31;
  const int bh = b * HEADS + hh;
  if (sec < 2) {
    _Float16* dst = (sec == 0) ? Qw : Kw;
    #pragma unroll
    for (int ns = 0; ns < 4; ++ns) {
      int p = p0 + ns * 16 + lm;
      half4 v = {(_Float16)acc[ns][0], (_Float16)acc[ns][1],
                 (_Float16)acc[ns][2], (_Float16)acc[ns][3]};
      *(half4*)(dst + ((size_t)bh * HW + p) * DH + dd) = v;
    }
  } else {
    #pragma unroll
    for (int ns = 0; ns < 4; ++ns) {
      int p = p0 + ns * 16 + lm;
      #pragma unroll
      for (int r = 0; r < 4; ++r)
        Vtw[((size_t)bh * DH + dd + r) * HW + p] = (_Float16)acc[ns][r];
    }
  }
}

// ---------------------------------------------------------------------------
// attn: register-dataflow flash attention, 2 q-tiles per wave (block covers
// 128 q-rows) so every K/V LDS read feeds 2x MFMA work — attacks the
// measured LDS-pipe bound. 128-wide K-step, ping-pong, one barrier per step.
// S^T = mfma(A=K-rows, B=Q^T, C=-SHIFT2); P^T stays in registers (16x16x16
// B-operand layout, HW-verified). O^T = V^T P^T; row sums via ones-MFMA.
// vt row stride 74 halves (37 dwords, odd) -> va reads spread all banks.
// grid (32 q-tiles, 16 bh) x 256.
// ---------------------------------------------------------------------------
__global__ __launch_bounds__(256) void attn(
    const _Float16* __restrict__ Qw, const _Float16* __restrict__ Kw,
    const _Float16* __restrict__ Vtw, _Float16* __restrict__ Ot)
{
  __shared__ _Float16 ks[2][2][64][40];       // [phase][sub][kcol][d]  40.0 KB
  __shared__ _Float16 vt[2][2][32][74];       // [phase][sub][d][kcol]  18.5 KB

  const int bh = blockIdx.y, qt = blockIdx.x;
  const int tid = threadIdx.x;
  const int wv = tid >> 6, lane = tid & 63, lm = lane & 15, quad = lane >> 4;

  const _Float16* qbase =
      Qw + ((size_t)bh * HW + qt * 128 + wv * 16 + lm) * DH + quad * 8;
  const half8 qa0 = *(const half8*)qbase;
  const half8 qa1 = *(const half8*)(qbase + (size_t)64 * DH);

  const _Float16 one = (_Float16)1.0f;
  const half4 ones4 = {one, one, one, one};
  const floatx4 shiftc = {-SHIFT2, -SHIFT2, -SHIFT2, -SHIFT2};

  floatx4 oT[2][2] = {{{0,0,0,0},{0,0,0,0}},{{0,0,0,0},{0,0,0,0}}};
  floatx4 l4[2]    = {{0,0,0,0},{0,0,0,0}};

  const _Float16* kbase = Kw  + (size_t)bh * HW * DH;
  const _Float16* vbase = Vtw + (size_t)bh * DH * HW;
  const int kr = tid >> 2, kc = (tid & 3) * 8;
  const int vr = tid >> 3, vc = (tid & 7) * 8;

  // prologue: stage subtiles 0,1; prefetch 2,3
  half8 kA = *(const half8*)(kbase + (size_t)kr * DH + kc);
  half8 vA = *(const half8*)(vbase + (size_t)vr * HW + vc);
  half8 kB = *(const half8*)(kbase + ((size_t)64 + kr) * DH + kc);
  half8 vB = *(const half8*)(vbase + (size_t)vr * HW + 64 + vc);
  *(half8*)&ks[0][0][kr][kc] = kA;
  *(half8*)&vt[0][0][vr][vc] = vA;
  *(half8*)&ks[0][1][kr][kc] = kB;
  *(half8*)&vt[0][1][vr][vc] = vB;
  kA = *(const half8*)(kbase + ((size_t)128 + kr) * DH + kc);
  vA = *(const half8*)(vbase + (size_t)vr * HW + 128 + vc);
  kB = *(const half8*)(kbase + ((size_t)192 + kr) * DH + kc);
  vB = *(const half8*)(vbase + (size_t)vr * HW + 192 + vc);
  __syncthreads();

  for (int it = 0; it < HW / 128; ++it) {
    const int ph = it & 1, nx = ph ^ 1;
    *(half8*)&ks[nx][0][kr][kc] = kA;
    *(half8*)&vt[nx][0][vr][vc] = vA;
    *(half8*)&ks[nx][1][kr][kc] = kB;
    *(half8*)&vt[nx][1][vr][vc] = vB;
    // prefetch subtiles (2it+4, 2it+5), clamped to stay in-bounds
    size_t koff = (size_t)(it * 2 + 4) * 64;
    if (koff > HW - 128) koff = HW - 128;
    kA = *(const half8*)(kbase + (koff + kr) * DH + kc);
    vA = *(const half8*)(vbase + (size_t)vr * HW + koff + vc);
    kB = *(const half8*)(kbase + (koff + 64 + kr) * DH + kc);
    vB = *(const half8*)(vbase + (size_t)vr * HW + koff + 64 + vc);

    #pragma unroll
    for (int sub = 0; sub < 2; ++sub) {
      #pragma unroll
      for (int f = 0; f < 4; ++f) {
        // S^T for both q-tiles off one kb read
        half8 kb = *(const half8*)&ks[ph][sub][f * 16 + lm][quad * 8];
        floatx4 sT0 = __builtin_amdgcn_mfma_f32_16x16x32_f16(kb, qa0, shiftc, 0, 0, 0);
        floatx4 sT1 = __builtin_amdgcn_mfma_f32_16x16x32_f16(kb, qa1, shiftc, 0, 0, 0);
        // P^T fragments in-register (packed cvt)
        half2v a0 = pk2(__builtin_amdgcn_exp2f(sT0[0]), __builtin_amdgcn_exp2f(sT0[1]));
        half2v b0 = pk2(__builtin_amdgcn_exp2f(sT0[2]), __builtin_amdgcn_exp2f(sT0[3]));
        half2v a1 = pk2(__builtin_amdgcn_exp2f(sT1[0]), __builtin_amdgcn_exp2f(sT1[1]));
        half2v b1 = pk2(__builtin_amdgcn_exp2f(sT1[2]), __builtin_amdgcn_exp2f(sT1[3]));
        half4 pb0 = {a0.x, a0.y, b0.x, b0.y};
        half4 pb1 = {a1.x, a1.y, b1.x, b1.y};
        l4[0] = __builtin_amdgcn_mfma_f32_16x16x16f16(ones4, pb0, l4[0], 0, 0, 0);
        l4[1] = __builtin_amdgcn_mfma_f32_16x16x16f16(ones4, pb1, l4[1], 0, 0, 0);
        #pragma unroll
        for (int g = 0; g < 2; ++g) {
          // one va read feeds both q-tiles' PV MFMAs
          half4 va = *(const half4*)&vt[ph][sub][g * 16 + lm][f * 16 + quad * 4];
          oT[0][g] = __builtin_amdgcn_mfma_f32_16x16x16f16(va, pb0, oT[0][g], 0, 0, 0);
          oT[1][g] = __builtin_amdgcn_mfma_f32_16x16x16f16(va, pb1, oT[1][g], 0, 0, 0);
        }
      }
    }
    __syncthreads();
  }

  // epilogue: lane-local normalize, coalesced half4 stores -> Ot[b][p][hid]
  const int b = bh >> 2, hh = bh & 3;
  #pragma unroll
  for (int t = 0; t < 2; ++t) {
    const float inv = 1.0f / l4[t][0];
    _Float16* obase = Ot +
        ((size_t)(b * HW + qt * 128 + t * 64 + wv * 16 + lm)) * HID + hh * DH;
    #pragma unroll
    for (int g = 0; g < 2; ++g) {
      half4 v = {(_Float16)(oT[t][g][0] * inv), (_Float16)(oT[t][g][1] * inv),
                 (_Float16)(oT[t][g][2] * inv), (_Float16)(oT[t][g][3] * inv)};
      *(half4*)(obase + g * 16 + quad * 4) = v;
    }
  }
}

// ---------------------------------------------------------------------------
// out_gemm: out[o][b,p] = w_out(256x128, cvt inline) @ Ot^T + bias.
// Tile 64x64, K=128. grid (4 m-tiles, 256 n-tiles) x 256.
// ---------------------------------------------------------------------------
__global__ __launch_bounds__(256) void out_gemm(
    const float* __restrict__ wo, const _Float16* __restrict__ Ot,
    const float* __restrict__ bo, float* __restrict__ out)
{
  __shared__ _Float16 As[64][136];
  __shared__ _Float16 Bs[64][136];
  __shared__ float os[64][68];
  const int mt = blockIdx.x, nt = blockIdx.y;
  const int b = nt >> 6, p0 = (nt & 63) * 64;
  const int tid = threadIdx.x;
  const int wv = tid >> 6, lane = tid & 63, lm = lane & 15, quad = lane >> 4;

  const float* Ag = wo + (size_t)(mt * 64) * HID;
  const _Float16* B = Ot + ((size_t)b * HW + p0) * HID;

  #pragma unroll
  for (int i = 0; i < 4; ++i) {
    int ci = tid + i * 256;
    int r = ci >> 4, c8 = (ci & 15) * 8;
    const float* src = Ag + (size_t)r * HID + c8;
    float4 u0 = *(const float4*)(src);
    float4 u1 = *(const float4*)(src + 4);
    half8 h = {(_Float16)u0.x, (_Float16)u0.y, (_Float16)u0.z, (_Float16)u0.w,
               (_Float16)u1.x, (_Float16)u1.y, (_Float16)u1.z, (_Float16)u1.w};
    *(half8*)&As[r][c8] = h;
    *(half8*)&Bs[r][c8] = *(const half8*)(B + (size_t)r * HID + c8);
  }
  __syncthreads();

  floatx4 acc[4] = {{0,0,0,0},{0,0,0,0},{0,0,0,0},{0,0,0,0}};
  #pragma unroll
  for (int ks = 0; ks < 4; ++ks) {
    half8 a = *(const half8*)&As[wv * 16 + lm][ks * 32 + quad * 8];
    #pragma unroll
    for (int ns = 0; ns < 4; ++ns) {
      half8 bf = *(const half8*)&Bs[ns * 16 + lm][ks * 32 + quad * 8];
      acc[ns] = __builtin_amdgcn_mfma_f32_16x16x32_f16(a, bf, acc[ns], 0, 0, 0);
    }
  }

  #pragma unroll
  for (int ns = 0; ns < 4; ++ns)
    #pragma unroll
    for (int r = 0; r < 4; ++r)
      os[wv * 16 + quad * 4 + r][ns * 16 + lm] = acc[ns][r];
  __syncthreads();

  const int o = tid >> 2, pq = (tid & 3) * 16;
  const float bias = bo[mt * 64 + o];
  float* dst = out + ((size_t)(b * CIN + mt * 64 + o)) * HW + p0 + pq;
  #pragma unroll
  for (int j = 0; j < 4; ++j) {
    float4 v = *(const float4*)&os[o][pq + j * 4];
    v.x += bias; v.y += bias; v.z += bias; v.w += bias;
    *(float4*)(dst + j * 4) = v;
  }
}

// ---------------------------------------------------------------------------
extern "C" void kernel_launch(void* const* d_in, const int* in_sizes, int n_in,
                              void* d_out, int out_size, void* d_ws, size_t ws_size,
                              hipStream_t stream)
{
  const float* x     = (const float*)d_in[0];   // [4,256,64,64]
  const float* w_qkv = (const float*)d_in[1];   // [384,256]
  const float* w_out = (const float*)d_in[2];   // [256,128]
  const float* b_out = (const float*)d_in[3];   // [256]
  float* out = (float*)d_out;

  char* ws = (char*)d_ws;
  _Float16* Ot  = (_Float16*)(ws);               // 4 MB [4][4096][128]
  _Float16* Qw  = (_Float16*)(ws + (8u  << 20)); // 4 MB [bh][p][d], log2e-scaled
  _Float16* Kw  = (_Float16*)(ws + (12u << 20)); // 4 MB [bh][p][d]
  _Float16* Vtw = (_Float16*)(ws + (16u << 20)); // 4 MB [bh][d][p]

  dim3 blk(256);
  qkv_fused<<<dim3(6, 256), blk, 0, stream>>>(w_qkv, x, Qw, Kw, Vtw);
  attn<<<dim3(32, 16), blk, 0, stream>>>(Qw, Kw, Vtw, Ot);
  out_gemm<<<dim3(4, 256), blk, 0, stream>>>(w_out, Ot, b_out, out);
}